// Round 13
// baseline (63.381 us; speedup 1.0000x reference)
//
#include <hip/hip_runtime.h>

// HSMNet feature_vol + channel-sum + softmax + disparity regression, fused.
// B=2, C=32, H=96, W=160, D=48. out[b,h,w] = sum_d softmax_d(score)*8d,
// score(w,d) = -(sum_c |ref[c,w]-tgt[c,w-d]|) for w>=d, else exactly 0.
//
// LDS layout [col][c] with STR=36 floats (144B): column starts 16B-aligned ->
// compute phase reads channels as ds_read_b128 (85 B/cyc vs 44 for b32);
// lanes step ct by 1 -> bank base steps 4 -> each 8-lane octet covers all 32
// banks: conflict-free. PARTS=8/DPP=6 (round-1 numeric grouping, absmax 1.0):
// per-block LDS reads 14336 b128 (-12.5% vs PARTS=16) and ref re-reads halved.

#define CCH  32
#define HH   96
#define WW   160
#define DD   48
#define TILE 32      // output columns per block
#define NT   5       // WW / TILE
#define PARTS 8      // d-parts per column
#define DPP  6       // d per part (PARTS*DPP == DD)
#define WIN  80      // staged tgt cols: w0-48 .. w0+31
#define STR  36      // floats per column: 16B-aligned, bank-rotating
#define NBLK (2 * HH * NT)   // 960

__global__ __launch_bounds__(256, 4)
void hsm_disp_kernel(const float* __restrict__ refp,
                     const float* __restrict__ tgtp,
                     float* __restrict__ out)
{
    __shared__ float tgt_l[WIN * STR];    // [col][c], c contiguous
    __shared__ float ref_l[TILE * STR];
    __shared__ float pm [PARTS * TILE];
    __shared__ float ps [PARTS * TILE];
    __shared__ float pws[PARTS * TILE];

    // Bijective XCD-aware swizzle: 960 = 8 XCDs * 120 chunks.
    int bx = blockIdx.x;
    int wg = (bx & 7) * (NBLK / 8) + (bx >> 3);

    int t  = wg % NT;
    int bh = wg / NT;
    int w0 = t * TILE;

    const size_t cs   = (size_t)HH * WW;
    const size_t base = (size_t)(bh / HH) * CCH * cs + (size_t)(bh % HH) * WW;

    const int tid = threadIdx.x;

    // ---- staging: coalesced b32 loads, ALL issued before any LDS store ----
    // tgt: 80 cols * 32 c = 2560 = 10*256 ; ref: 32*32 = 1024 = 4*256.
    float tv[10]; int tct[10], tcc[10];
    #pragma unroll
    for (int k = 0; k < 10; ++k) {
        int i  = tid + k * 256;
        int c  = i / WIN;
        int ct = i - c * WIN;
        int gc = w0 - 48 + ct;                  // global col, may be < 0
        tct[k] = ct; tcc[k] = c;
        tv[k] = (gc >= 0) ? tgtp[base + (size_t)c * cs + gc] : 0.0f;
    }
    float rv2[4]; int rct[4], rcc[4];
    #pragma unroll
    for (int k = 0; k < 4; ++k) {
        int i  = tid + k * 256;
        int c  = i >> 5;
        int cl = i & 31;
        rct[k] = cl; rcc[k] = c;
        rv2[k] = refp[base + (size_t)c * cs + (w0 + cl)];
    }
    #pragma unroll
    for (int k = 0; k < 10; ++k) tgt_l[tct[k] * STR + tcc[k]] = tv[k];
    #pragma unroll
    for (int k = 0; k < 4; ++k) ref_l[rct[k] * STR + rcc[k]] = rv2[k];
    __syncthreads();

    // ---- compute: thread = (col cl, part p), 6 d's per part, b128 reads ----
    const int cl = tid & 31;
    const int p  = tid >> 5;          // 0..7
    const int d0 = p * DPP;
    const int w  = w0 + cl;

    const int ct0 = cl - d0 + 48;     // stream-0 column in [6,79]; ct0-5 >= 1
    const float4* tq0 = (const float4*)&tgt_l[(ct0    ) * STR];
    const float4* tq1 = (const float4*)&tgt_l[(ct0 - 1) * STR];
    const float4* tq2 = (const float4*)&tgt_l[(ct0 - 2) * STR];
    const float4* tq3 = (const float4*)&tgt_l[(ct0 - 3) * STR];
    const float4* tq4 = (const float4*)&tgt_l[(ct0 - 4) * STR];
    const float4* tq5 = (const float4*)&tgt_l[(ct0 - 5) * STR];
    const float4* rb  = (const float4*)&ref_l[cl * STR];

    float a0 = 0.f, a1 = 0.f, a2 = 0.f, a3 = 0.f, a4 = 0.f, a5 = 0.f;
    #pragma unroll
    for (int cq = 0; cq < CCH / 4; ++cq) {
        float4 rv = rb[cq];
        float4 t0 = tq0[cq];
        float4 t1 = tq1[cq];
        float4 t2 = tq2[cq];
        float4 t3 = tq3[cq];
        float4 t4 = tq4[cq];
        float4 t5 = tq5[cq];
        a0 += fabsf(rv.x - t0.x) + fabsf(rv.y - t0.y)
            + fabsf(rv.z - t0.z) + fabsf(rv.w - t0.w);
        a1 += fabsf(rv.x - t1.x) + fabsf(rv.y - t1.y)
            + fabsf(rv.z - t1.z) + fabsf(rv.w - t1.w);
        a2 += fabsf(rv.x - t2.x) + fabsf(rv.y - t2.y)
            + fabsf(rv.z - t2.z) + fabsf(rv.w - t2.w);
        a3 += fabsf(rv.x - t3.x) + fabsf(rv.y - t3.y)
            + fabsf(rv.z - t3.z) + fabsf(rv.w - t3.w);
        a4 += fabsf(rv.x - t4.x) + fabsf(rv.y - t4.y)
            + fabsf(rv.z - t4.z) + fabsf(rv.w - t4.w);
        a5 += fabsf(rv.x - t5.x) + fabsf(rv.y - t5.y)
            + fabsf(rv.z - t5.z) + fabsf(rv.w - t5.w);
    }
    float sc[DPP];
    sc[0] = (w >= d0)     ? -a0 : 0.f;   // masked cells: score exactly 0
    sc[1] = (w >= d0 + 1) ? -a1 : 0.f;
    sc[2] = (w >= d0 + 2) ? -a2 : 0.f;
    sc[3] = (w >= d0 + 3) ? -a3 : 0.f;
    sc[4] = (w >= d0 + 4) ? -a4 : 0.f;
    sc[5] = (w >= d0 + 5) ? -a5 : 0.f;

    // partial softmax stats over this part's 6 d values (round-1 grouping)
    float m = sc[0];
    #pragma unroll
    for (int j = 1; j < DPP; ++j) m = fmaxf(m, sc[j]);
    float s = 0.0f, ws = 0.0f;
    #pragma unroll
    for (int j = 0; j < DPP; ++j) {
        float e = __expf(sc[j] - m);
        s  += e;
        ws += e * (float)((d0 + j) * 8);
    }
    pm [p * TILE + cl] = m;
    ps [p * TILE + cl] = s;
    pws[p * TILE + cl] = ws;
    __syncthreads();

    // ---- merge 8 partials per column ----
    if (tid < TILE) {
        float M = pm[tid];
        #pragma unroll
        for (int q = 1; q < PARTS; ++q) M = fmaxf(M, pm[q * TILE + tid]);
        float S = 0.f, WS = 0.f;
        #pragma unroll
        for (int q = 0; q < PARTS; ++q) {
            float f = __expf(pm[q * TILE + tid] - M);
            S  += ps [q * TILE + tid] * f;
            WS += pws[q * TILE + tid] * f;
        }
        out[(size_t)bh * WW + w0 + tid] = WS / S;
    }
}

extern "C" void kernel_launch(void* const* d_in, const int* in_sizes, int n_in,
                              void* d_out, int out_size, void* d_ws, size_t ws_size,
                              hipStream_t stream) {
    const float* left  = (const float*)d_in[0];   // ref
    const float* right = (const float*)d_in[1];   // tgt
    float* outp = (float*)d_out;
    (void)in_sizes; (void)n_in; (void)out_size; (void)d_ws; (void)ws_size;

    hsm_disp_kernel<<<dim3(NBLK), dim3(256), 0, stream>>>(left, right, outp);
}